// Round 1
// baseline (71.078 us; speedup 1.0000x reference)
//
#include <hip/hip_runtime.h>

// Ball query: for each of NQ=32768 query points g (p_grid), find the first
// K=10 indices i (ascending) of x (N2=8192 points) with
//   d2 = (|g|^2 + |x_i|^2) - 2*dot(g, x_i) <= 0.25^2
// Output (concat, float32): mapping [NQ,K] (index as float, 0 if unfound),
//                           points  [NQ,K,3] (x_i coords, 0 if unfound).
//
// Strategy: one 64-lane wave per query; scan x in chunks of 64 candidates,
// ballot the validity mask, extract first valid indices by prefix-popcount
// rank, early-exit once K found. Exact-FP32 (unfused, left-to-right) distance
// to match the numpy reference bit-for-bit at the radius boundary.

#define BQ_K   10
#define BQ_N2  8192
#define BQ_NQ  32768
#define BQ_R2  0.0625f

__global__ __launch_bounds__(256) void bq_kernel(
    const float* __restrict__ x,      // [N2,3]
    const float* __restrict__ pg,     // [NQ,3]
    float* __restrict__ map_out,      // [NQ,K]
    float* __restrict__ pts_out)      // [NQ,K,3]
{
    const int lane = threadIdx.x & 63;
    const int q = (int)blockIdx.x * 4 + (threadIdx.x >> 6);   // wave per query
    if (q >= BQ_NQ) return;

    // Query point (uniform per wave; broadcast via cache).
    const float gx = pg[q * 3 + 0];
    const float gy = pg[q * 3 + 1];
    const float gz = pg[q * 3 + 2];
    // |g|^2, left-to-right, unfused (matches np.sum(p1*p1, -1)).
    const float gg = __fadd_rn(__fadd_rn(__fmul_rn(gx, gx), __fmul_rn(gy, gy)),
                               __fmul_rn(gz, gz));

    float* __restrict__ mo = map_out + (size_t)q * BQ_K;
    float* __restrict__ po = pts_out + (size_t)q * BQ_K * 3;

    int found = 0;   // wave-uniform count of valid points seen so far

    for (int base = 0; base < BQ_N2; base += 64) {
        const int i = base + lane;
        const float xv = x[i * 3 + 0];
        const float yv = x[i * 3 + 1];
        const float zv = x[i * 3 + 2];

        // |x|^2 and dot(g,x), left-to-right, unfused.
        const float xx = __fadd_rn(__fadd_rn(__fmul_rn(xv, xv), __fmul_rn(yv, yv)),
                                   __fmul_rn(zv, zv));
        const float dt = __fadd_rn(__fadd_rn(__fmul_rn(gx, xv), __fmul_rn(gy, yv)),
                                   __fmul_rn(gz, zv));
        // d2 = (gg + xx) - 2*dt   (exactly the reference's association)
        const float d2 = __fsub_rn(__fadd_rn(gg, xx), __fmul_rn(2.0f, dt));

        const bool valid = (d2 <= BQ_R2);
        const unsigned long long m = __ballot(valid);
        if (m != 0ull) {
            if (valid) {
                const int rank = __popcll(m & ((1ull << lane) - 1ull));
                const int slot = found + rank;
                if (slot < BQ_K) {
                    mo[slot] = (float)i;             // mapping as float value
                    po[slot * 3 + 0] = xv;
                    po[slot * 3 + 1] = yv;
                    po[slot * 3 + 2] = zv;
                }
            }
            found += __popcll(m);
            if (found >= BQ_K) break;                // uniform early exit
        }
    }

    // Zero-fill unfound slots (d_out is poisoned 0xAA before every launch).
    const int filled = found < BQ_K ? found : BQ_K;
    if (lane < BQ_K && lane >= filled) {
        mo[lane] = 0.0f;
        po[lane * 3 + 0] = 0.0f;
        po[lane * 3 + 1] = 0.0f;
        po[lane * 3 + 2] = 0.0f;
    }
}

extern "C" void kernel_launch(void* const* d_in, const int* in_sizes, int n_in,
                              void* d_out, int out_size, void* d_ws, size_t ws_size,
                              hipStream_t stream) {
    const float* x  = (const float*)d_in[0];   // (1, 8192, 3) float32
    const float* pg = (const float*)d_in[1];   // (1, 64, 32, 16, 3) float32
    float* out = (float*)d_out;
    float* map_out = out;                      // [NQ*K]
    float* pts_out = out + (size_t)BQ_NQ * BQ_K;  // [NQ*K*3]

    // One wave per query: 32768 queries / 4 waves per 256-thread block.
    bq_kernel<<<BQ_NQ / 4, 256, 0, stream>>>(x, pg, map_out, pts_out);
}